// Round 8
// baseline (774.815 us; speedup 1.0000x reference)
//
#include <hip/hip_runtime.h>
#include <hip/hip_bf16.h>

// Transducer joint: logits[b,t,u,v] = tanh(enc_proj[b,t,:]+dec_proj[b,u,:]+b1) @ W2 + b2
// B=4 T=256 U=128, ENC=DEC=512, INNER=512, VOCAB=2048
// R8: persistent staggered GEMM. 512 blocks (2/CU), each owns one my-panel
//     (256 rows) and sweeps ny=0..15 (loop -> epilogue per tile). Odd half
//     sleeps ~5us at start so CU-mates run antiphase: one block's K-loop
//     covers the other's store drain. Ring-3 LDS + b2 in LDS = 80 KB.

typedef __attribute__((ext_vector_type(4))) float f32x4;
typedef __attribute__((ext_vector_type(8))) __bf16 bf16x8;
typedef __attribute__((ext_vector_type(8))) unsigned short u16x8;

__device__ __forceinline__ float bf2f(unsigned short u) {
  unsigned int x = ((unsigned int)u) << 16;
  return __builtin_bit_cast(float, x);
}
__device__ __forceinline__ unsigned short f2bf(float f) {
  unsigned int x = __builtin_bit_cast(unsigned int, f);
  x += 0x7fff + ((x >> 16) & 1);   // RNE
  return (unsigned short)(x >> 16);
}
__device__ __forceinline__ float tanh_fast(float x) {
  float e = __expf(2.0f * x);
  return 1.0f - 2.0f * __builtin_amdgcn_rcpf(e + 1.0f);
}

typedef __attribute__((address_space(3))) unsigned int lds_u32;
typedef const __attribute__((address_space(1))) unsigned int glb_u32;
__device__ __forceinline__ void gl16(const void* g, void* l) {
  __builtin_amdgcn_global_load_lds((glb_u32*)g, (lds_u32*)l, 16, 0, 0);
}

#define BAR __builtin_amdgcn_s_barrier()
#define LGKM0 asm volatile("s_waitcnt lgkmcnt(0)" ::: "memory")
#define VMCNT(n) asm volatile("s_waitcnt vmcnt(" #n ")" ::: "memory")
#define MEMPIN asm volatile("" ::: "memory")

// ---------------- Pass 1: proj (x-in-LDS broadcast GEMM) ----------------
__global__ __launch_bounds__(512) void proj8_kernel(
    const float* __restrict__ enc, const float* __restrict__ dec,
    const float* __restrict__ W1, const float* __restrict__ b1,
    float* __restrict__ enc_proj, unsigned short* __restrict__ decb) {
  __shared__ float xs[8][512];
  const int bid = blockIdx.x;
  const bool isenc = bid < 128;
  const int rows0 = (isenc ? bid : bid - 128) * 8;
  const float* src = (isenc ? enc : dec) + (size_t)rows0 * 512;
  const int tid = threadIdx.x;
#pragma unroll
  for (int j = 0; j < 2; ++j) {
    int v = j * 512 + tid;
    int row = v >> 7;
    int c4 = (v & 127) << 2;
    *(f32x4*)&xs[row][c4] = *(const f32x4*)&src[(size_t)row * 512 + c4];
  }
  __syncthreads();
  const int h = tid;
  const float* wp = W1 + (isenc ? 0 : (size_t)512 * 512) + h;
  float acc[8];
  float init = isenc ? 0.f : b1[h];
#pragma unroll
  for (int r = 0; r < 8; ++r) acc[r] = init;
#pragma unroll 4
  for (int k = 0; k < 512; ++k) {
    float wv = wp[(size_t)k * 512];
#pragma unroll
    for (int r = 0; r < 8; ++r) acc[r] = fmaf(xs[r][k], wv, acc[r]);
  }
  if (isenc) {
#pragma unroll
    for (int r = 0; r < 8; ++r) enc_proj[(size_t)(rows0 + r) * 512 + h] = acc[r];
  } else {
#pragma unroll
    for (int r = 0; r < 8; ++r) decb[(size_t)(rows0 + r) * 512 + h] = f2bf(acc[r]);
  }
}

// ---------------- Pass 2: W2 [512][2048] fp32 -> W2t [2048][512] bf16 ----------------
__global__ __launch_bounds__(256) void w2t_kernel(const float* __restrict__ W2,
                                                  unsigned short* __restrict__ W2t) {
  __shared__ unsigned short tile[32][33];
  int bn = blockIdx.x;
  int bk = blockIdx.y;
  int tx = threadIdx.x & 31;
  int ty = threadIdx.x >> 5;
#pragma unroll
  for (int i = 0; i < 32; i += 8)
    tile[ty + i][tx] = f2bf(W2[(size_t)(bk * 32 + ty + i) * 2048 + bn * 32 + tx]);
  __syncthreads();
#pragma unroll
  for (int i = 0; i < 32; i += 8)
    W2t[(size_t)(bn * 32 + ty + i) * 512 + bk * 32 + tx] = tile[tx][ty + i];
}

// ---------------- Pass 3: H[m][h] = tanh(encp[bt][h] + decb[bu][h]) bf16 ----------------
__global__ __launch_bounds__(256) void h_kernel(
    const float* __restrict__ encp, const unsigned short* __restrict__ decb,
    unsigned short* __restrict__ Hout) {
  int gid = blockIdx.x * 256 + threadIdx.x;
  int m = gid >> 6;
  int hc = (gid & 63) << 3;
  int bt = m >> 7;
  int bu = ((m >> 15) << 7) | (m & 127);
  u16x8 dv = *(const u16x8*)(decb + (size_t)bu * 512 + hc);
  f32x4 e0 = *(const f32x4*)(encp + (size_t)bt * 512 + hc);
  f32x4 e1 = *(const f32x4*)(encp + (size_t)bt * 512 + hc + 4);
  u16x8 hv;
#pragma unroll
  for (int j = 0; j < 4; ++j) hv[j] = f2bf(tanh_fast(bf2f(dv[j]) + e0[j]));
#pragma unroll
  for (int j = 0; j < 4; ++j) hv[4 + j] = f2bf(tanh_fast(bf2f(dv[4 + j]) + e1[j]));
  *(u16x8*)(Hout + (size_t)m * 512 + hc) = hv;
}

// ---------------- Pass 4: persistent staggered BM=256 BN=128 BK=32 GEMM ----------------
// LDS: ring 3 x 24576 (A 16K + B 8K per slot) + b2 8 KB = 81920 B (80 KB).
// Per tile: 16 phases (vmcnt(3) steady; phases 0,1 after an epilogue: vmcnt(19)
// = 16 stores + 1 prefetched batch in flight). Epilogue: transpose via the
// just-freed ring slot in two 4-wave rounds, nt full-line stores.

__global__ __launch_bounds__(512, 4) void gemmps_kernel(
    const unsigned short* __restrict__ H,     // [131072][512] bf16
    const unsigned short* __restrict__ W2t,   // [2048][512] bf16
    const float* __restrict__ b2,             // [2048]
    float* __restrict__ out) {                // [131072][2048] fp32
  __shared__ __align__(1024) char smem[81920];

  const int bid = blockIdx.x;      // 512
  const int my = bid & 511;        // one panel per block

  const int tid = threadIdx.x;
  const int lane = tid & 63;
  const int w = tid >> 6;
  const int wm = w >> 1;     // 0..3
  const int wn = w & 1;      // 0..1
  const int fr = lane & 15;
  const int fq = lane >> 4;

  // gl16 source offsets (dest linear; src pre-swizzled: chunk c of row r from c^(r&3))
  size_t srcA[2], srcB;
#pragma unroll
  for (int p = 0; p < 2; ++p) {
    int d = p * 8192 + w * 1024 + lane * 16;
    int r = d >> 6;
    int c = (d >> 4) & 3;
    srcA[p] = (size_t)r * 1024 + (size_t)((c ^ (r & 3)) << 4);
  }
  {
    int d = w * 1024 + lane * 16;
    int r = d >> 6;
    int c = (d >> 4) & 3;
    srcB = (size_t)r * 1024 + (size_t)((c ^ (r & 3)) << 4);
  }

  const int swz = (fq ^ (fr & 3)) << 4;
  const int ldsA = (wm * 64 + fr) * 64 + swz;            // + mi*1024
  const int ldsB = 16384 + (wn * 64 + fr) * 64 + swz;    // + ni*1024

  const char* ha = (const char*)H + ((size_t)my << 18);  // A panel (256 rows x 1024 B)
  float* b2l = (float*)(smem + 73728);

  // b2 -> LDS, clean ledger start
  {
    f32x4 bchunk = *(const f32x4*)&b2[tid * 4];
    *(f32x4*)&b2l[tid * 4] = bchunk;
  }
  __syncthreads();

  // stagger: second dispatch-round blocks (CU-mates) sleep ~5us
  if (bid >= 256) {
    asm volatile("s_sleep 127");
    asm volatile("s_sleep 64");
  }

  f32x4 acc[4][4];
#pragma unroll
  for (int i = 0; i < 4; ++i)
#pragma unroll
    for (int j = 0; j < 4; ++j) acc[i][j] = (f32x4){0.f, 0.f, 0.f, 0.f};

  const int rrow = lane >> 4;
  const int rcol = (lane & 15) * 4;

#define STAGEG2(tg_, ks_, sl_)                                           \
  do {                                                                   \
    char* slp_ = smem + (sl_)*24576;                                     \
    const char* wb_ = (const char*)W2t + ((size_t)(tg_) << 17);          \
    gl16(ha + srcA[0] + (ks_)*64, slp_ + w * 1024);                      \
    gl16(ha + srcA[1] + (ks_)*64, slp_ + 8192 + w * 1024);               \
    gl16(wb_ + srcB + (ks_)*64, slp_ + 16384 + w * 1024);                \
  } while (0)

  // prologue: tile0 batches 0,1 -> slots 0,1
  STAGEG2(0, 0, 0);
  STAGEG2(0, 1, 1);

  int sl = 0;   // slot of current batch
  int sp = 2;   // slot for prefetch (current+2)

#pragma unroll 1
  for (int tt = 0; tt < 16; ++tt) {
#pragma unroll
    for (int p = 0; p < 16; ++p) {
      // per-wave in-order vmcnt ledger:
      //  steady: 1 batch ahead in flight -> wait 3
      //  p<2 after an epilogue: +16 stores -> wait 19
      //  very last phase: nothing beyond -> 0
      if (tt == 15 && p == 15) {
        VMCNT(0);
      } else if (p < 2) {
        if (tt > 0) { VMCNT(19); } else { VMCNT(3); }
      } else {
        VMCNT(3);
      }
      BAR; MEMPIN;

      const char* As = smem + sl * 24576;
      bf16x8 a4[4], b4[4];
#pragma unroll
      for (int mi = 0; mi < 4; ++mi) a4[mi] = *(const bf16x8*)(As + ldsA + mi * 1024);
#pragma unroll
      for (int ni = 0; ni < 4; ++ni) b4[ni] = *(const bf16x8*)(As + ldsB + ni * 1024);

      // prefetch batch (tt,p)+2
      if (!(tt == 15 && p >= 14)) {
        const int ks2 = (p + 2) & 15;
        const int tg2 = tt + ((p + 2) >> 4);
        STAGEG2(tg2, ks2, sp);
      }
      LGKM0;

      __builtin_amdgcn_s_setprio(1);
#pragma unroll
      for (int mi = 0; mi < 4; ++mi)
#pragma unroll
        for (int ni = 0; ni < 4; ++ni)
          acc[mi][ni] = __builtin_amdgcn_mfma_f32_16x16x32_bf16(
              a4[mi], b4[ni], acc[mi][ni], 0, 0, 0);
      __builtin_amdgcn_s_setprio(0);

      const int slc = sl;   // slot just consumed (free after the barrier below)
      sl = (sl == 2) ? 0 : sl + 1;
      sp = (sp == 2) ? 0 : sp + 1;

      if (p == 15) {
        // ---- epilogue for tile tt: borrow freed slot, 2 wave-group rounds ----
        BAR; MEMPIN;   // all waves done reading batch; slot slc free
        const size_t rbase = ((size_t)my << 8) + wm * 64;
        const int ncol0 = tt * 128 + wn * 64;
        float bvv[4];
#pragma unroll
        for (int ni = 0; ni < 4; ++ni) bvv[ni] = b2l[ncol0 + ni * 16 + fr];

        char* slotp = smem + slc * 24576;
        if (w < 4) {
          float* ls = (float*)slotp + w * 1088;   // 16 x 68 f32
#pragma unroll
          for (int mi = 0; mi < 4; ++mi) {
#pragma unroll
            for (int ni = 0; ni < 4; ++ni)
#pragma unroll
              for (int r = 0; r < 4; ++r)
                ls[(fq * 4 + r) * 68 + ni * 16 + fr] = acc[mi][ni][r] + bvv[ni];
#pragma unroll
            for (int j = 0; j < 4; ++j) {
              const int row = j * 4 + rrow;
              f32x4 v = *(const f32x4*)&ls[row * 68 + rcol];
              __builtin_nontemporal_store(
                  v, (f32x4*)&out[(rbase + mi * 16 + row) * 2048 + ncol0 + rcol]);
            }
          }
        }
        BAR; MEMPIN;
        if (w >= 4) {
          float* ls = (float*)slotp + (w - 4) * 1088;
#pragma unroll
          for (int mi = 0; mi < 4; ++mi) {
#pragma unroll
            for (int ni = 0; ni < 4; ++ni)
#pragma unroll
              for (int r = 0; r < 4; ++r)
                ls[(fq * 4 + r) * 68 + ni * 16 + fr] = acc[mi][ni][r] + bvv[ni];
#pragma unroll
            for (int j = 0; j < 4; ++j) {
              const int row = j * 4 + rrow;
              f32x4 v = *(const f32x4*)&ls[row * 68 + rcol];
              __builtin_nontemporal_store(
                  v, (f32x4*)&out[(rbase + mi * 16 + row) * 2048 + ncol0 + rcol]);
            }
          }
        }
        // reset accumulators for next tile
#pragma unroll
        for (int i = 0; i < 4; ++i)
#pragma unroll
          for (int j = 0; j < 4; ++j) acc[i][j] = (f32x4){0.f, 0.f, 0.f, 0.f};
      }
    }
  }
#undef STAGEG2
}

extern "C" void kernel_launch(void* const* d_in, const int* in_sizes, int n_in,
                              void* d_out, int out_size, void* d_ws, size_t ws_size,
                              hipStream_t stream) {
  const float* enc = (const float*)d_in[0];
  const float* dec = (const float*)d_in[1];
  const float* W1  = (const float*)d_in[2];
  const float* b1  = (const float*)d_in[3];
  const float* W2  = (const float*)d_in[4];
  const float* b2  = (const float*)d_in[5];
  float* out = (float*)d_out;

  char* ws = (char*)d_ws;
  float* enc_proj = (float*)ws;                                    // 2 MB
  unsigned short* decb = (unsigned short*)(ws + (2u << 20));       // 512 KB
  unsigned short* W2t  = (unsigned short*)(ws + (2u << 20) + (512u << 10)); // 2 MB
  unsigned short* Hbuf = (unsigned short*)(ws + (8u << 20));       // 134.25 MB

  proj8_kernel<<<192, 512, 0, stream>>>(enc, dec, W1, b1, enc_proj, decb);
  w2t_kernel<<<dim3(64, 16), 256, 0, stream>>>(W2, W2t);
  h_kernel<<<32768, 256, 0, stream>>>(enc_proj, decb, Hbuf);
  gemmps_kernel<<<512, 512, 0, stream>>>(Hbuf, W2t, b2, out);
}